// Round 6
// baseline (321.980 us; speedup 1.0000x reference)
//
#include <hip/hip_runtime.h>
#include <cstdint>
#include <cstddef>

typedef float f4 __attribute__((ext_vector_type(4)));
typedef float f32x4 __attribute__((ext_vector_type(4)));
typedef short short8 __attribute__((ext_vector_type(8)));
typedef unsigned short u16x8 __attribute__((ext_vector_type(8)));
typedef unsigned short u16x4 __attribute__((ext_vector_type(4)));
typedef unsigned short ushort_t;

#define B_   32
#define C_   768
#define HW_  1024
#define DQ_  16
#define K_   64
#define M_   1024
#define NHWT 16
#define NCT  12     // C_/64
#define NHALF 72    // 3 terms x 12 K-tiles x 2 K-halves

#define CODE_OFF 524288
#define LOSS_OFF 524320

// ---------------- bf16 split helpers (RNE) ----------------
__device__ __forceinline__ unsigned bf16_rne_bits(float x) {
    unsigned u = __builtin_bit_cast(unsigned, x);
    return (u + 0x7FFFu + ((u >> 16) & 1u)) >> 16;
}
__device__ __forceinline__ float bits_to_f32(unsigned hi16) {
    unsigned u = hi16 << 16;
    return __builtin_bit_cast(float, u);
}
__device__ __forceinline__ void split_bf16(float x, unsigned short& hi, unsigned short& lo) {
    unsigned h = bf16_rne_bits(x);
    hi = (unsigned short)h;
    float r = x - bits_to_f32(h);
    lo = (unsigned short)bf16_rne_bits(r);
}

// ============================================================
// Split-tensor layout (K-tiled, contiguous K-tiles of 64 c):
//   Whi/Wlo :  [ct(12)][m(1024)][cl(64)]
//   FhiT/FloT: [b(32)][ct(12)][hw(1024)][cl(64)]
// ============================================================

// ============================================================
// K0a: split + transpose features F[b][c][hw] -> tiled layout
// ============================================================
__global__ __launch_bounds__(256)
void k0_splitF(const float* __restrict__ Fp,
               ushort_t* __restrict__ FhiT, ushort_t* __restrict__ FloT)
{
    __shared__ float tile[64][65];
    const int t = threadIdx.x;
    const int ht = blockIdx.x, ct = blockIdx.y, b = blockIdx.z;

#pragma unroll
    for (int rep = 0; rep < 4; ++rep) {
        int idx = rep * 256 + t;
        int c_l = idx >> 4;
        int hwf = (idx & 15) * 4;
        f4 v = *(const f4*)&Fp[((size_t)b * C_ + ct * 64 + c_l) * HW_ + ht * 64 + hwf];
        tile[c_l][hwf + 0] = v.x;
        tile[c_l][hwf + 1] = v.y;
        tile[c_l][hwf + 2] = v.z;
        tile[c_l][hwf + 3] = v.w;
    }
    __syncthreads();

#pragma unroll
    for (int rep = 0; rep < 2; ++rep) {
        int hw_l = (t >> 3) + rep * 32;
        int cg   = (t & 7) * 8;
        unsigned short hi[8], lo[8];
#pragma unroll
        for (int j = 0; j < 8; ++j)
            split_bf16(tile[cg + j][hw_l], hi[j], lo[j]);
        size_t o = (((size_t)(b * NCT + ct)) * HW_ + ht * 64 + hw_l) * 64 + cg;
        *(u16x8*)&FhiT[o] = *(u16x8*)hi;
        *(u16x8*)&FloT[o] = *(u16x8*)lo;
    }
}

// ============================================================
// K0b: split W[m(1024)][c(768)] -> tiled layout [ct][m][64]
// ============================================================
__global__ __launch_bounds__(256)
void k0_splitW(const float* __restrict__ Wp,
               ushort_t* __restrict__ Whi, ushort_t* __restrict__ Wlo)
{
    const unsigned gid = blockIdx.x * 256 + threadIdx.x;
    const unsigned base = gid * 4;                 // flat [m][c]
    const unsigned m = base / C_;
    const unsigned c = base - m * C_;
    const unsigned ct = c >> 6, cl = c & 63;
    f4 v = *(const f4*)&Wp[base];
    unsigned short hi[4], lo[4];
    split_bf16(v.x, hi[0], lo[0]);
    split_bf16(v.y, hi[1], lo[1]);
    split_bf16(v.z, hi[2], lo[2]);
    split_bf16(v.w, hi[3], lo[3]);
    size_t o = ((size_t)ct * M_ + m) * 64 + cl;
    *(u16x4*)&Whi[o] = *(u16x4*)hi;
    *(u16x4*)&Wlo[o] = *(u16x4*)lo;
}

// ============================================================
// K1: 256x256 MFMA GEMM over concatenated K=2304, ring-4 K-half
// pipeline with counted vmcnt(8) (never 0 in the main loop).
// LDS: 4 slots x 32KB (A-half 16KB @0, B-half 16KB @8192 ush).
// Slot layout (per tensor): byte(row, ks) = (row>>1)*128 +
//   ((((row&1)*4 + ks) ^ ((row>>1)&7)) * 16)   [ks = 16B k-slot 0..3]
// -> staged with linear 1KB dests + per-lane permuted global src;
//    frag ds_read_b128 conflict-free (2 lanes/16B-pos per quarter-wave).
// ============================================================
__global__ __launch_bounds__(512, 1)
void k1_mfma8(const ushort_t* __restrict__ Whi, const ushort_t* __restrict__ Wlo,
              const ushort_t* __restrict__ FhiT, const ushort_t* __restrict__ FloT,
              const float* __restrict__ Qp, float* __restrict__ partial)
{
    __shared__ ushort_t lds[4][16384];   // 4 x 32KB

    const int tid  = threadIdx.x;
    const int w    = tid >> 6;
    const int lane = tid & 63;

    const int bid = blockIdx.x;
    const int idx = (bid & 7) * 64 + (bid >> 3);   // bijective XCD swizzle
    const int mt  = idx & 3;
    const int hwt = (idx >> 2) & 3;
    const int b   = idx >> 4;

    const int wm = w >> 2, wn = w & 3;

    // staging roles: waves 0-3 stage the A half (rows wgrp*64..+63),
    // waves 4-7 stage the B half.
    const bool isA   = (w < 4);
    const int  wgrp  = w & 3;
    const int  regoff = isA ? 0 : 8192;            // ushort units

    // per-lane stage source permutation (lane L's 16B lands at L*16 in the
    // 1KB chunk; invert the skew to find which (row, ks) belongs there)
    const int q_l  = lane >> 3;          // 0..7
    const int p_l  = lane & 7;
    const int t_l  = p_l ^ (q_l & 7);
    const int rloc_l = 2 * q_l + (t_l >> 2);   // row within 16-row chunk
    const int ks_l   = t_l & 3;

    // fragment ds_read offsets (ushort units, slot-relative)
    const int c15 = lane & 15, d0 = lane >> 4;   // d0 = k-slot 0..3
    int offA[8], offB[4];
#pragma unroll
    for (int i = 0; i < 8; ++i) {
        int r = wm * 128 + i * 16 + c15;
        int q = r >> 1;
        offA[i] = q * 64 + (((((r & 1) << 2) | d0) ^ (q & 7)) << 3);
    }
#pragma unroll
    for (int j = 0; j < 4; ++j) {
        int r = wn * 64 + j * 16 + c15;
        int q = r >> 1;
        offB[j] = 8192 + q * 64 + (((((r & 1) << 2) | d0) ^ (q & 7)) << 3);
    }

    f32x4 acc[8][4] = {};

    // computes the stage source base + LDS dest for half gg
#define STAGE_SETUP(GG)                                                                  \
    const int stile = (GG) >> 1, shalf = (GG) & 1;                                       \
    const int sterm = (stile >= 24) ? 2 : ((stile >= 12) ? 1 : 0);                       \
    const int sct   = stile - sterm * 12;                                                \
    const ushort_t* sb;                                                                  \
    if (isA) sb = ((sterm == 1) ? Wlo : Whi) + ((size_t)sct * M_ + mt * 256) * 64;       \
    else     sb = ((sterm == 2) ? FloT : FhiT) + ((size_t)(b * NCT + sct) * HW_ + hwt * 256) * 64; \
    sb += shalf * 32 + (size_t)(wgrp * 64 + rloc_l) * 64 + ks_l * 8;                     \
    ushort_t* Dst = &lds[(GG) & 3][regoff + wgrp * 2048];

#define STAGE1(II)                                                                       \
    __builtin_amdgcn_global_load_lds(                                                    \
        (const __attribute__((address_space(1))) void*)(sb + (II) * 1024),               \
        (__attribute__((address_space(3))) void*)(Dst + (II) * 512),                     \
        16, 0, 0);

    // ---- prologue: stage halves 0,1,2 into slots 0,1,2 ----
#pragma unroll
    for (int h = 0; h < 3; ++h) {
        STAGE_SETUP(h)
        STAGE1(0) STAGE1(1) STAGE1(2) STAGE1(3)
    }
    asm volatile("s_waitcnt vmcnt(8)" ::: "memory");   // half 0 landed
    __builtin_amdgcn_s_barrier();

    short8 af[4], bf[4];

    for (int g = 0; g < NHALF; ++g) {
        const ushort_t* L = &lds[g & 3][0];
        const int ggw = g + 3;
        const int gg  = (ggw >= NHALF) ? ggw - NHALF : ggw;  // wrap: dummy stages at tail
        STAGE_SETUP(gg)

        // ---------- phase A: af0-3 + bf0-3 reads; stage 0,1; MFMA i0-3 ----------
#pragma unroll
        for (int i = 0; i < 4; ++i) af[i] = *(const short8*)&L[offA[i]];
#pragma unroll
        for (int j = 0; j < 4; ++j) bf[j] = *(const short8*)&L[offB[j]];
        STAGE1(0) STAGE1(1)
        __builtin_amdgcn_s_barrier();
        asm volatile("s_waitcnt lgkmcnt(0)" ::: "memory");
        __builtin_amdgcn_sched_barrier(0);
        __builtin_amdgcn_s_setprio(1);
#pragma unroll
        for (int i = 0; i < 4; ++i)
#pragma unroll
            for (int j = 0; j < 4; ++j)
                acc[i][j] = __builtin_amdgcn_mfma_f32_16x16x32_bf16(af[i], bf[j], acc[i][j], 0, 0, 0);
        __builtin_amdgcn_s_setprio(0);
        __builtin_amdgcn_sched_barrier(0);
        __builtin_amdgcn_s_barrier();

        // ---------- phase B: af4-7 reads; stage 2,3; MFMA i4-7 ----------
#pragma unroll
        for (int i = 0; i < 4; ++i) af[i] = *(const short8*)&L[offA[4 + i]];
        STAGE1(2) STAGE1(3)
        __builtin_amdgcn_s_barrier();
        asm volatile("s_waitcnt lgkmcnt(0)" ::: "memory");
        __builtin_amdgcn_sched_barrier(0);
        __builtin_amdgcn_s_setprio(1);
#pragma unroll
        for (int i = 0; i < 4; ++i)
#pragma unroll
            for (int j = 0; j < 4; ++j)
                acc[4 + i][j] = __builtin_amdgcn_mfma_f32_16x16x32_bf16(af[i], bf[j], acc[4 + i][j], 0, 0, 0);
        __builtin_amdgcn_s_setprio(0);
        __builtin_amdgcn_sched_barrier(0);
        asm volatile("s_waitcnt vmcnt(8)" ::: "memory");   // counted: half g+1 landed
        __builtin_amdgcn_s_barrier();
    }
#undef STAGE1
#undef STAGE_SETUP

    // ---- epilogue: (Q - kv)^2, per-k wave reduction ----
    float qv[4][4];
#pragma unroll
    for (int j = 0; j < 4; ++j) {
        const int hw = hwt * 256 + wn * 64 + j * 16 + c15;
#pragma unroll
        for (int r = 0; r < 4; ++r)
            qv[j][r] = Qp[(size_t)(b * DQ_ + d0 * 4 + r) * HW_ + hw];
    }
#pragma unroll
    for (int i = 0; i < 8; ++i) {
        float s = 0.f;
#pragma unroll
        for (int j = 0; j < 4; ++j)
#pragma unroll
            for (int r = 0; r < 4; ++r) {
                float d = qv[j][r] - acc[i][j][r];
                s = fmaf(d, d, s);
            }
#pragma unroll
        for (int off = 32; off; off >>= 1) s += __shfl_xor(s, off);
        if (lane == 0) {
            const int k = mt * 16 + wm * 8 + i;
            partial[((size_t)b * K_ + k) * NHWT + hwt * 4 + wn] = s;
        }
    }
}

// ============================================================
// K2: reduce partials -> argmin + loss
// ============================================================
__global__ __launch_bounds__(1024)
void k2_select(const float* __restrict__ partial, float* __restrict__ out,
               int* __restrict__ codes_ws)
{
    const int tid = threadIdx.x;
    const int b = tid >> 5, kk = tid & 31;
    float s0 = 0.f, s1 = 0.f;
#pragma unroll
    for (int h = 0; h < NHWT; ++h) {
        s0 += partial[((size_t)b * K_ + kk) * NHWT + h];
        s1 += partial[((size_t)b * K_ + kk + 32) * NHWT + h];
    }
    float bv = s0; int bk = kk;
    if (s1 < bv) { bv = s1; bk = kk + 32; }
#pragma unroll
    for (int m = 16; m >= 1; m >>= 1) {
        float ov = __shfl_xor(bv, m);
        int   ok = __shfl_xor(bk, m);
        if (ov < bv || (ov == bv && ok < bk)) { bv = ov; bk = ok; }
    }
    __shared__ float mins[32];
    if (kk == 0) {
        out[CODE_OFF + b] = (float)bk;
        codes_ws[b] = bk;
        mins[b] = bv;
    }
    __syncthreads();
    if (tid == 0) {
        float t = 0.f;
#pragma unroll
        for (int i = 0; i < 32; ++i) t += mins[i];
        out[LOSS_OFF] = t * (1.0f / 524288.0f);
    }
}

// ============================================================
// K3: sel via bf16-triple MFMA from split tensors.
// ============================================================
__global__ __launch_bounds__(256)
void k3_mfma(const ushort_t* __restrict__ Whi, const ushort_t* __restrict__ Wlo,
             const ushort_t* __restrict__ FhiT, const ushort_t* __restrict__ FloT,
             const int* __restrict__ codes_ws, float* __restrict__ out)
{
    __shared__ ushort_t lds3[2][10240];  // A:32 rows @0 (hi 0-15, lo 16-31); Bhi @2048; Blo @6144

    const int tid = threadIdx.x;
    const int w = tid >> 6, lane = tid & 63;
    const int b = blockIdx.x >> 4, hwt = blockIdx.x & 15;
    const int code = codes_ws[b];

    const int srow = lane >> 3, sslot = (lane & 7) ^ srow;
    const int c15 = lane & 15, d0 = lane >> 4;

    int offAhi[2], offAlo[2], offBh[2], offBl[2];
#pragma unroll
    for (int kh = 0; kh < 2; ++kh) {
        const int d = kh * 4 + d0;
        const int mA = c15;
        offAhi[kh] = mA * 64 + ((d ^ (mA & 7)) << 3);
        const int mAl = 16 + c15;
        offAlo[kh] = mAl * 64 + ((d ^ (mAl & 7)) << 3);
        const int rB = w * 16 + c15;
        offBh[kh] = 2048 + rB * 64 + ((d ^ (rB & 7)) << 3);
        offBl[kh] = 6144 + rB * 64 + ((d ^ (rB & 7)) << 3);
    }

#define K3_STAGE(CT, BUF)                                                                        \
    {                                                                                            \
        ushort_t* Lb = &lds3[(BUF)][0];                                                          \
        const ushort_t* bhp = FhiT + ((size_t)(b * NCT + (CT)) * HW_ + hwt * 64) * 64;           \
        const ushort_t* blp = FloT + ((size_t)(b * NCT + (CT)) * HW_ + hwt * 64) * 64;           \
        _Pragma("unroll")                                                                        \
        for (int ii = 0; ii < 2; ++ii) {                                                         \
            __builtin_amdgcn_global_load_lds(                                                    \
                (const __attribute__((address_space(1))) void*)(bhp + (w * 16 + ii * 8 + srow) * 64 + sslot * 8), \
                (__attribute__((address_space(3))) void*)(Lb + 2048 + (w * 16 + ii * 8) * 64),   \
                16, 0, 0);                                                                       \
            __builtin_amdgcn_global_load_lds(                                                    \
                (const __attribute__((address_space(1))) void*)(blp + (w * 16 + ii * 8 + srow) * 64 + sslot * 8), \
                (__attribute__((address_space(3))) void*)(Lb + 6144 + (w * 16 + ii * 8) * 64),   \
                16, 0, 0);                                                                       \
        }                                                                                        \
        if (w == 0) {                                                                            \
            const ushort_t* ahp = Whi + ((size_t)(CT) * M_ + code * 16) * 64;                    \
            _Pragma("unroll")                                                                    \
            for (int ii = 0; ii < 2; ++ii)                                                       \
                __builtin_amdgcn_global_load_lds(                                                \
                    (const __attribute__((address_space(1))) void*)(ahp + (ii * 8 + srow) * 64 + sslot * 8), \
                    (__attribute__((address_space(3))) void*)(Lb + (ii * 8) * 64),               \
                    16, 0, 0);                                                                   \
        } else if (w == 1) {                                                                     \
            const ushort_t* alp = Wlo + ((size_t)(CT) * M_ + code * 16) * 64;                    \
            _Pragma("unroll")                                                                    \
            for (int ii = 0; ii < 2; ++ii)                                                       \
                __builtin_amdgcn_global_load_lds(                                                \
                    (const __attribute__((address_space(1))) void*)(alp + (ii * 8 + srow) * 64 + sslot * 8), \
                    (__attribute__((address_space(3))) void*)(Lb + (16 + ii * 8) * 64),          \
                    16, 0, 0);                                                                   \
        }                                                                                        \
    }

    f32x4 acc = {};

    K3_STAGE(0, 0)
    asm volatile("s_waitcnt vmcnt(0)" ::: "memory");
    __syncthreads();

    for (int ct = 0; ct < NCT; ++ct) {
        const int cur = ct & 1;
        if (ct + 1 < NCT) K3_STAGE(ct + 1, cur ^ 1)
        const ushort_t* L = &lds3[cur][0];
        short8 ah[2], al2[2], bh[2], bl[2];
#pragma unroll
        for (int kh = 0; kh < 2; ++kh) {
            ah[kh]  = *(const short8*)&L[offAhi[kh]];
            al2[kh] = *(const short8*)&L[offAlo[kh]];
            bh[kh]  = *(const short8*)&L[offBh[kh]];
            bl[kh]  = *(const short8*)&L[offBl[kh]];
        }
#pragma unroll
        for (int kh = 0; kh < 2; ++kh) {
            acc = __builtin_amdgcn_mfma_f32_16x16x32_bf16(ah[kh], bh[kh], acc, 0, 0, 0);
            acc = __builtin_amdgcn_mfma_f32_16x16x32_bf16(ah[kh], bl[kh], acc, 0, 0, 0);
            acc = __builtin_amdgcn_mfma_f32_16x16x32_bf16(al2[kh], bh[kh], acc, 0, 0, 0);
        }
        asm volatile("s_waitcnt vmcnt(0)" ::: "memory");
        __syncthreads();
    }
#undef K3_STAGE

#pragma unroll
    for (int r = 0; r < 4; ++r) {
        const int q = d0 * 4 + r;
        out[((size_t)(b * DQ_ + q)) * HW_ + hwt * 64 + w * 16 + c15] = acc[r];
    }
}

// ============================================================
// Fallback tier (ws too small): fp32 VALU path, old layouts
// ============================================================
#define BM   256
#define BN   64
#define BC   32
#define NMT  4

__global__ __launch_bounds__(256)
void k1_dist_fp32(const float* __restrict__ Fp, const float* __restrict__ Qp,
                  const float* __restrict__ Wp, float* __restrict__ partial)
{
    __shared__ float w_lds[BC][BM];
    __shared__ float f_lds[BC][BN + 8];
    __shared__ float red[32][8];

    const int tid = threadIdx.x;
    const int mt = blockIdx.x, hwt = blockIdx.y, b = blockIdx.z;
    const int ty = tid >> 3, tx = tid & 7;
    const int m0 = ty * 8, hw0 = tx * 8;

    float acc[8][8];
#pragma unroll
    for (int i = 0; i < 8; ++i)
#pragma unroll
        for (int j = 0; j < 8; ++j) acc[i][j] = 0.f;

    for (int c0 = 0; c0 < C_; c0 += BC) {
#pragma unroll
        for (int i = 0; i < 8; ++i) {
            const int m_l = i * 32 + ty;
            const int c_l = tx * 4;
            const int col = m_l ^ (tx * 4);
            f4 w4 = *(const f4*)&Wp[(size_t)(mt * BM + m_l) * C_ + c0 + c_l];
            w_lds[c_l + 0][col] = w4.x;
            w_lds[c_l + 1][col] = w4.y;
            w_lds[c_l + 2][col] = w4.z;
            w_lds[c_l + 3][col] = w4.w;
        }
        {
            const int c = tid >> 3;
            const int hw = (tid & 7) * 8;
            const float* src = &Fp[((size_t)b * C_ + c0 + c) * HW_ + (size_t)hwt * BN + hw];
            *(f4*)&f_lds[c][hw]     = *(const f4*)src;
            *(f4*)&f_lds[c][hw + 4] = *(const f4*)(src + 4);
        }
        __syncthreads();

#pragma unroll 4
        for (int cc = 0; cc < BC; ++cc) {
            const int sw = ((cc >> 2) & 7) * 4;
            const int colA = m0 ^ sw;
            f4 w0 = *(const f4*)&w_lds[cc][colA];
            f4 w1 = *(const f4*)&w_lds[cc][colA ^ 4];
            f4 g0 = *(const f4*)&f_lds[cc][hw0];
            f4 g1 = *(const f4*)&f_lds[cc][hw0 + 4];
            const float wa[8] = {w0.x, w0.y, w0.z, w0.w, w1.x, w1.y, w1.z, w1.w};
            const float fv[8] = {g0.x, g0.y, g0.z, g0.w, g1.x, g1.y, g1.z, g1.w};
#pragma unroll
            for (int i = 0; i < 8; ++i)
#pragma unroll
                for (int j = 0; j < 8; ++j)
                    acc[i][j] = fmaf(wa[i], fv[j], acc[i][j]);
        }
        __syncthreads();
    }

    const int q0 = (ty & 1) * 8;
    float s = 0.f;
#pragma unroll
    for (int i = 0; i < 8; ++i) {
        const float* qp = &Qp[((size_t)b * DQ_ + q0 + i) * HW_ + (size_t)hwt * BN + hw0];
        f4 qa = *(const f4*)qp;
        f4 qb = *(const f4*)(qp + 4);
        float d;
        d = qa.x - acc[i][0]; s = fmaf(d, d, s);
        d = qa.y - acc[i][1]; s = fmaf(d, d, s);
        d = qa.z - acc[i][2]; s = fmaf(d, d, s);
        d = qa.w - acc[i][3]; s = fmaf(d, d, s);
        d = qb.x - acc[i][4]; s = fmaf(d, d, s);
        d = qb.y - acc[i][5]; s = fmaf(d, d, s);
        d = qb.z - acc[i][6]; s = fmaf(d, d, s);
        d = qb.w - acc[i][7]; s = fmaf(d, d, s);
    }
    red[ty][tx] = s;
    __syncthreads();
    if (tid < 16) {
        float t = 0.f;
#pragma unroll
        for (int r = 0; r < 2; ++r)
#pragma unroll
            for (int x = 0; x < 8; ++x) t += red[tid * 2 + r][x];
        partial[((size_t)b * K_ + mt * 16 + tid) * NHWT + hwt] = t;
    }
}

#define BN3 128
#define BC3 32

__global__ __launch_bounds__(256)
void k3_sel(const float* __restrict__ Fp, const float* __restrict__ Wp,
            const int* __restrict__ codes_ws, float* __restrict__ out)
{
    __shared__ float f_lds[BC3][BN3];
    __shared__ float w_lds[DQ_][33];

    const int tid = threadIdx.x;
    const int b = blockIdx.x >> 3, hwt = blockIdx.x & 7;
    const int code = codes_ws[b];
    const int q = tid >> 4;
    const int hw0 = (tid & 15) * 8;

    float a[8] = {0.f, 0.f, 0.f, 0.f, 0.f, 0.f, 0.f, 0.f};

    for (int c0 = 0; c0 < C_; c0 += BC3) {
        if (tid < 128) {
            const int qq = tid >> 3, c4 = (tid & 7) * 4;
            f4 w4 = *(const f4*)&Wp[((size_t)code * DQ_ + qq) * C_ + c0 + c4];
            w_lds[qq][c4 + 0] = w4.x;
            w_lds[qq][c4 + 1] = w4.y;
            w_lds[qq][c4 + 2] = w4.z;
            w_lds[qq][c4 + 3] = w4.w;
        }
        {
            const int c = tid >> 3;
            const int hw = (tid & 7) * 16;
            const float* src = &Fp[((size_t)b * C_ + c0 + c) * HW_ + (size_t)hwt * BN3 + hw];
            *(f4*)&f_lds[c][hw]      = *(const f4*)(src);
            *(f4*)&f_lds[c][hw + 4]  = *(const f4*)(src + 4);
            *(f4*)&f_lds[c][hw + 8]  = *(const f4*)(src + 8);
            *(f4*)&f_lds[c][hw + 12] = *(const f4*)(src + 12);
        }
        __syncthreads();
#pragma unroll 4
        for (int cc = 0; cc < BC3; ++cc) {
            const float wv = w_lds[q][cc];
            f4 g0 = *(const f4*)&f_lds[cc][hw0];
            f4 g1 = *(const f4*)&f_lds[cc][hw0 + 4];
            a[0] = fmaf(wv, g0.x, a[0]);
            a[1] = fmaf(wv, g0.y, a[1]);
            a[2] = fmaf(wv, g0.z, a[2]);
            a[3] = fmaf(wv, g0.w, a[3]);
            a[4] = fmaf(wv, g1.x, a[4]);
            a[5] = fmaf(wv, g1.y, a[5]);
            a[6] = fmaf(wv, g1.z, a[6]);
            a[7] = fmaf(wv, g1.w, a[7]);
        }
        __syncthreads();
    }

    float* dst = &out[((size_t)b * DQ_ + q) * HW_ + (size_t)hwt * BN3 + hw0];
    f4 o0 = {a[0], a[1], a[2], a[3]};
    f4 o1 = {a[4], a[5], a[6], a[7]};
    *(f4*)dst = o0;
    *(f4*)(dst + 4) = o1;
}

// ============================================================
extern "C" void kernel_launch(void* const* d_in, const int* in_sizes, int n_in,
                              void* d_out, int out_size, void* d_ws, size_t ws_size,
                              hipStream_t stream)
{
    const float* Fp = (const float*)d_in[0];
    const float* Qp = (const float*)d_in[1];
    const float* Wp = (const float*)d_in[2];
    float* out = (float*)d_out;

    const size_t FT_ELEMS = (size_t)B_ * HW_ * C_;
    const size_t W_ELEMS  = (size_t)M_ * C_;
    const size_t PART_OFF = 4 * FT_ELEMS + 4 * W_ELEMS;
    const size_t CODE_WS  = PART_OFF + (size_t)B_ * K_ * NHWT * 4;
    const size_t NEED     = CODE_WS + 128;

    if (ws_size >= NEED) {
        ushort_t* FhiT = (ushort_t*)d_ws;
        ushort_t* FloT = FhiT + FT_ELEMS;
        ushort_t* Whi  = FloT + FT_ELEMS;
        ushort_t* Wlo  = Whi + W_ELEMS;
        float* partial = (float*)((char*)d_ws + PART_OFF);
        int* codes_ws  = (int*)((char*)d_ws + CODE_WS);

        k0_splitF<<<dim3(16, NCT, B_), 256, 0, stream>>>(Fp, FhiT, FloT);
        k0_splitW<<<dim3(W_ELEMS / 1024), 256, 0, stream>>>(Wp, Whi, Wlo);
        k1_mfma8<<<dim3(512), 512, 0, stream>>>(Whi, Wlo, FhiT, FloT, Qp, partial);
        k2_select<<<1, 1024, 0, stream>>>(partial, out, codes_ws);
        k3_mfma<<<dim3(B_ * 16), 256, 0, stream>>>(Whi, Wlo, FhiT, FloT, codes_ws, out);
    } else {
        float* partial = (float*)d_ws;
        int* codes_ws  = (int*)((char*)d_ws + (size_t)B_ * K_ * NHWT * 4);
        k1_dist_fp32<<<dim3(NMT, NHWT, B_), 256, 0, stream>>>(Fp, Qp, Wp, partial);
        k2_select<<<1, 1024, 0, stream>>>(partial, out, codes_ws);
        k3_sel<<<dim3(B_ * 8), 256, 0, stream>>>(Fp, Wp, codes_ws, out);
    }
}